// Round 7
// baseline (152.334 us; speedup 1.0000x reference)
//
#include <hip/hip_runtime.h>
#include <hip/hip_bf16.h>

#define DDIM 448
#define NSTEP 14            // 448 / 32
#define ASTRIDE 456         // padded LDS leading dim (bf16 elems)

typedef __hip_bfloat16 bf16;
typedef __attribute__((ext_vector_type(8))) short short8;   // 8 bf16 = 16B (MFMA A/B frag)
typedef __attribute__((ext_vector_type(4))) float f32x4;    // MFMA C/D frag / float4

__device__ __forceinline__ short bf_bits(float f) {
    bf16 h = __float2bfloat16(f);
    return *reinterpret_cast<short*>(&h);
}

// ---------------------------------------------------------------------------
// Kernel 1: WcT[o][i] = sum_d Wo[d][o] * E[i][d],
//           E[i][d] = Wq[i][d]*diagA[d] + Wk[i][d]*diagB[d] + Wv[i][d]*diagC[d]
// (unchanged — passed since R4, ~4 µs)
// ---------------------------------------------------------------------------
__global__ __launch_bounds__(256) void prep_wc(
    const float* __restrict__ Wq, const float* __restrict__ Wk,
    const float* __restrict__ Wv, const float* __restrict__ Wo,
    const float* __restrict__ Ad, const float* __restrict__ Bd,
    const float* __restrict__ Cd, bf16* __restrict__ WcT)
{
    __shared__ __align__(16) bf16 As[64 * 32];
    __shared__ __align__(16) bf16 Bs[64 * 32];
    __shared__ float da[DDIM], db[DDIM], dc[DDIM];

    const int tid  = threadIdx.x;
    const int i0   = blockIdx.x * 64;
    const int o0   = blockIdx.y * 64;
    const int lane = tid & 63;
    const int wid  = tid >> 6;
    const int wm   = wid >> 1, wn = wid & 1;
    const int m_   = lane & 15, kq = lane >> 4;

    for (int d = tid; d < DDIM; d += 256) {
        da[d] = Ad[d * DDIM + d];
        db[d] = Bd[d * DDIM + d];
        dc[d] = Cd[d * DDIM + d];
    }

    const int dr  = tid >> 3;
    const int oc8 = (tid & 7) * 8;
    const int ir  = tid >> 2;
    const int dc8 = (tid & 3) * 8;

    f32x4 acc[2][2] = {};

    f32x4 w0 = *(const f32x4*)(Wo + dr * DDIM + o0 + oc8);
    f32x4 w1 = *(const f32x4*)(Wo + dr * DDIM + o0 + oc8 + 4);
    f32x4 q0 = *(const f32x4*)(Wq + (i0 + ir) * DDIM + dc8);
    f32x4 q1 = *(const f32x4*)(Wq + (i0 + ir) * DDIM + dc8 + 4);
    f32x4 t0 = *(const f32x4*)(Wk + (i0 + ir) * DDIM + dc8);
    f32x4 t1 = *(const f32x4*)(Wk + (i0 + ir) * DDIM + dc8 + 4);
    f32x4 v0 = *(const f32x4*)(Wv + (i0 + ir) * DDIM + dc8);
    f32x4 v1 = *(const f32x4*)(Wv + (i0 + ir) * DDIM + dc8 + 4);

    for (int k0 = 0; k0 < DDIM; k0 += 32) {
        __syncthreads();
        #pragma unroll
        for (int j = 0; j < 4; ++j) {
            As[(oc8 + j) * 32 + dr]     = __float2bfloat16(w0[j]);
            As[(oc8 + 4 + j) * 32 + dr] = __float2bfloat16(w1[j]);
        }
        short8 e;
        #pragma unroll
        for (int j = 0; j < 4; ++j) {
            e[j]     = bf_bits(q0[j] * da[k0 + dc8 + j]
                             + t0[j] * db[k0 + dc8 + j]
                             + v0[j] * dc[k0 + dc8 + j]);
            e[j + 4] = bf_bits(q1[j] * da[k0 + dc8 + 4 + j]
                             + t1[j] * db[k0 + dc8 + 4 + j]
                             + v1[j] * dc[k0 + dc8 + 4 + j]);
        }
        *(short8*)&Bs[ir * 32 + dc8] = e;
        __syncthreads();

        const int kn = (k0 + 32 < DDIM) ? k0 + 32 : 0;
        w0 = *(const f32x4*)(Wo + (kn + dr) * DDIM + o0 + oc8);
        w1 = *(const f32x4*)(Wo + (kn + dr) * DDIM + o0 + oc8 + 4);
        q0 = *(const f32x4*)(Wq + (i0 + ir) * DDIM + kn + dc8);
        q1 = *(const f32x4*)(Wq + (i0 + ir) * DDIM + kn + dc8 + 4);
        t0 = *(const f32x4*)(Wk + (i0 + ir) * DDIM + kn + dc8);
        t1 = *(const f32x4*)(Wk + (i0 + ir) * DDIM + kn + dc8 + 4);
        v0 = *(const f32x4*)(Wv + (i0 + ir) * DDIM + kn + dc8);
        v1 = *(const f32x4*)(Wv + (i0 + ir) * DDIM + kn + dc8 + 4);

        short8 af[2], bfr[2];
        #pragma unroll
        for (int mi = 0; mi < 2; ++mi)
            af[mi] = *(const short8*)&As[(wm * 32 + mi * 16 + m_) * 32 + kq * 8];
        #pragma unroll
        for (int ni = 0; ni < 2; ++ni)
            bfr[ni] = *(const short8*)&Bs[(wn * 32 + ni * 16 + m_) * 32 + kq * 8];
        #pragma unroll
        for (int mi = 0; mi < 2; ++mi)
            #pragma unroll
            for (int ni = 0; ni < 2; ++ni)
                acc[mi][ni] = __builtin_amdgcn_mfma_f32_16x16x32_bf16(
                    af[mi], bfr[ni], acc[mi][ni], 0, 0, 0);
    }

    #pragma unroll
    for (int mi = 0; mi < 2; ++mi)
        #pragma unroll
        for (int ni = 0; ni < 2; ++ni) {
            const int o = o0 + wm * 32 + mi * 16 + kq * 4;
            const int i = i0 + wn * 32 + ni * 16 + m_;
            #pragma unroll
            for (int r = 0; r < 4; ++r)
                WcT[(o + r) * DDIM + i] = __float2bfloat16(acc[mi][ni][r]);
        }
}

// ---------------------------------------------------------------------------
// Kernel 2: out[M x 448](fp32) = X(fp32) @ Wc   (WcT bf16, o-major, i contig)
// 512 threads / 8 waves (2 waves/SIMD), 256 blocks = 1/CU.
// Phase 1: stage the whole 128x448 A-panel to LDS (bf16, stride 456), 1 barrier.
// Phase 2: 14 K-steps with NO barriers: A-frags via ds_read_b128; B-frags
//          loaded per-wave directly from L2-resident WcT (dwordx4), manually
//          software-pipelined one step ahead (unroll-by-2, no reg copies).
// Phase 3: epilogue, 4 stages of 32 rows through an LDS bounce (aliases A).
// Waves: wv = 2x4 grid; wm=wv>>2 picks 64 rows, wn=wv&3 picks 112 cols.
// ---------------------------------------------------------------------------
__global__ __launch_bounds__(512, 2) void gemm_xwc(
    const float* __restrict__ X, const bf16* __restrict__ WcT,
    float* __restrict__ out)
{
    __shared__ __align__(16) char smem[128 * ASTRIDE * 2];   // 114 KB
    bf16* As = (bf16*)smem;

    const int tid  = threadIdx.x;
    const int lane = tid & 63;
    const int wv   = tid >> 6;               // 0..7
    const int wm   = wv >> 2;                // 0..1 : 64-row half
    const int wn   = wv & 3;                 // 0..3 : 112-col quarter
    const int m_   = lane & 15;
    const int kq   = lane >> 4;
    const int row0 = blockIdx.x * 128;

    // ---- Phase 1: stage A-panel (128 x 448 fp32 -> bf16 LDS) ----
    {
        const int ar  = tid >> 2;            // 0..127
        const int ac  = (tid & 3) * 8;       // 0,8,16,24
        const float* agp = X + (row0 + ar) * DDIM + ac;
        #pragma unroll
        for (int ko = 0; ko < NSTEP; ++ko) {
            f32x4 x0 = *(const f32x4*)(agp + ko * 32);
            f32x4 x1 = *(const f32x4*)(agp + ko * 32 + 4);
            short8 w;
            #pragma unroll
            for (int j = 0; j < 4; ++j) {
                w[j]     = bf_bits(x0[j]);
                w[j + 4] = bf_bits(x1[j]);
            }
            *(short8*)&As[ar * ASTRIDE + ko * 32 + ac] = w;
        }
    }
    __syncthreads();                         // the ONLY pre-epilogue barrier

    // ---- Phase 2: K-loop, barrier-free ----
    const bf16* bgp = WcT + (wn * 112 + m_) * DDIM + kq * 8;  // +ni*16*DDIM +k
    const int arow = wm * 64;

    f32x4 acc[4][7] = {};
    short8 b0[7], b1[7];
    #pragma unroll
    for (int ni = 0; ni < 7; ++ni)
        b0[ni] = *(const short8*)(bgp + ni * 16 * DDIM);

    for (int s = 0; s < NSTEP; s += 2) {
        // half 1: consume b0 (step s), prefetch b1 = B(s+1)
        #pragma unroll
        for (int ni = 0; ni < 7; ++ni)
            b1[ni] = *(const short8*)(bgp + ni * 16 * DDIM + (s + 1) * 32);
        {
            short8 af[4];
            #pragma unroll
            for (int mi = 0; mi < 4; ++mi)
                af[mi] = *(const short8*)&As[(arow + mi * 16 + m_) * ASTRIDE
                                             + s * 32 + kq * 8];
            #pragma unroll
            for (int mi = 0; mi < 4; ++mi)
                #pragma unroll
                for (int ni = 0; ni < 7; ++ni)
                    acc[mi][ni] = __builtin_amdgcn_mfma_f32_16x16x32_bf16(
                        af[mi], b0[ni], acc[mi][ni], 0, 0, 0);
        }
        // half 2: consume b1 (step s+1), prefetch b0 = B(s+2)
        if (s + 2 < NSTEP) {                 // uniform
            #pragma unroll
            for (int ni = 0; ni < 7; ++ni)
                b0[ni] = *(const short8*)(bgp + ni * 16 * DDIM + (s + 2) * 32);
        }
        {
            short8 af[4];
            #pragma unroll
            for (int mi = 0; mi < 4; ++mi)
                af[mi] = *(const short8*)&As[(arow + mi * 16 + m_) * ASTRIDE
                                             + (s + 1) * 32 + kq * 8];
            #pragma unroll
            for (int mi = 0; mi < 4; ++mi)
                #pragma unroll
                for (int ni = 0; ni < 7; ++ni)
                    acc[mi][ni] = __builtin_amdgcn_mfma_f32_16x16x32_bf16(
                        af[mi], b1[ni], acc[mi][ni], 0, 0, 0);
        }
    }

    // ---- Phase 3: epilogue, 4 stages of 32 rows via LDS bounce ----
    float* Cb = (float*)smem;                // 32 x 448 fp32 = 56 KB (aliases As)
    #pragma unroll
    for (int t = 0; t < 4; ++t) {
        __syncthreads();                     // As reads / prior stage done
        if (wm == (t >> 1)) {                // wave-uniform
            #pragma unroll
            for (int p = 0; p < 2; ++p) {
                const int mi = (t & 1) * 2 + p;
                #pragma unroll
                for (int ni = 0; ni < 7; ++ni) {
                    const int col = wn * 112 + ni * 16 + m_;
                    #pragma unroll
                    for (int r = 0; r < 4; ++r)
                        Cb[(p * 16 + kq * 4 + r) * DDIM + col] = acc[mi][ni][r];
                }
            }
        }
        __syncthreads();
        float* dst = out + (row0 + t * 32) * DDIM;   // 32x448 contiguous
        #pragma unroll
        for (int j = 0; j < 7; ++j)
            ((f32x4*)dst)[j * 512 + tid] = ((const f32x4*)Cb)[j * 512 + tid];
    }
}

// ---------------------------------------------------------------------------
extern "C" void kernel_launch(void* const* d_in, const int* in_sizes, int n_in,
                              void* d_out, int out_size, void* d_ws, size_t ws_size,
                              hipStream_t stream) {
    const float* x  = (const float*)d_in[0];
    const float* Wq = (const float*)d_in[1];
    const float* Wk = (const float*)d_in[2];
    const float* Wv = (const float*)d_in[3];
    const float* Wo = (const float*)d_in[4];
    const float* Ad = (const float*)d_in[5];
    const float* Bd = (const float*)d_in[6];
    const float* Cd = (const float*)d_in[7];

    bf16*  WcT = (bf16*)d_ws;                      // 448*448*2 = 392 KiB scratch
    float* out = (float*)d_out;

    const int M = in_sizes[0] / DDIM;              // 32768

    prep_wc<<<dim3(7, 7), 256, 0, stream>>>(Wq, Wk, Wv, Wo, Ad, Bd, Cd, WcT);
    gemm_xwc<<<M / 128, 512, 0, stream>>>(x, WcT, out);
}